// Round 8
// baseline (82.980 us; speedup 1.0000x reference)
//
#include <hip/hip_runtime.h>
#include <math.h>

#define N_NODES 2000
#define N_EDGES 32000
#define BB 16
#define TT 20
#define NG (BB*TT)      // 320 graphs
#define OUTF 8
#define HID 24
#define FC_OUTD 160
#define FCC_OUTD 20
#define EPT 32                 // edges per thread (32000 = 1000 * 32 exactly)
#define NTE (N_EDGES/EPT)      // 1000 active edge-threads

// ws layout (bytes)
#define WS_CSRPOS   0          // u32[32000]
#define WS_META     131072     // u32[32000] tiled as int4 [8][NTE]
#define WS_ROWPTR   262144     // int[2001]
#define WS_CURSOR   270336     // int[2000]
#define WS_FEATS    278528     // float[NG*OUTF]
#define WS_M        290816     // float[480]
#define WS_B2       292864     // float[20]

// ---------------- builder A: histogram + scan -> row_ptr, zero cursor ----------------

__global__ __launch_bounds__(1024) void build_hist_scan(
    const int* __restrict__ dst, int* __restrict__ row_ptr, int* __restrict__ cursor)
{
    __shared__ int a[2048], b[2048];
    const int tid = threadIdx.x;
    a[tid] = 0; a[tid + 1024] = 0;
    __syncthreads();
    for (int e = tid; e < N_EDGES; e += 1024) atomicAdd(&a[dst[e]], 1);
    __syncthreads();
    int *s = a, *d = b;
    for (int off = 1; off < 2048; off <<= 1) {
        d[tid] = s[tid] + (tid >= off ? s[tid - off] : 0);
        const int j = tid + 1024;
        d[j] = s[j] + (j >= off ? s[j - off] : 0);
        __syncthreads();
        int* t = s; s = d; d = t;
    }
    if (tid == 0) row_ptr[0] = 0;
    for (int i = tid; i < N_NODES; i += 1024) {
        row_ptr[i + 1] = s[i];
        cursor[i] = 0;
    }
}

// ------- builder B: scatter edges to CSR positions (+ extra block: fused fc@fcc) -------

__global__ __launch_bounds__(1024) void build_scatter(
    const int* __restrict__ src, const int* __restrict__ dst,
    const int* __restrict__ row_ptr, int* __restrict__ cursor,
    unsigned* __restrict__ meta, unsigned* __restrict__ csr_pos,
    const float* __restrict__ fc_w, const float* __restrict__ fc_b,
    const float* __restrict__ fcc_w, const float* __restrict__ fcc_b,
    float* __restrict__ Mout, float* __restrict__ b2out)
{
    const int tid = threadIdx.x;
    if (blockIdx.x == 32) {     // prep block: M = fcc_w @ fc_w ; b2 = fcc_b + fcc_w @ fc_b
        if (tid < FCC_OUTD * HID) {
            const int j = tid / HID, h = tid % HID;
            float acc = 0.f;
#pragma unroll 4
            for (int m = 0; m < FC_OUTD; ++m)
                acc += fcc_w[j * FC_OUTD + m] * fc_w[m * HID + h];
            Mout[tid] = acc;
        } else if (tid < FCC_OUTD * HID + FCC_OUTD) {
            const int j = tid - FCC_OUTD * HID;
            float acc = fcc_b[j];
#pragma unroll 4
            for (int m = 0; m < FC_OUTD; ++m)
                acc += fcc_w[j * FC_OUTD + m] * fc_b[m];
            b2out[j] = acc;
        }
        return;
    }
    const int e = blockIdx.x * 1024 + tid;
    if (e >= N_EDGES) return;
    const int s = src[e], d = dst[e];
    const int rp  = row_ptr[d];
    const int pos = rp + atomicAdd(&cursor[d], 1);
    const unsigned fl = (pos == rp) ? 1u : 0u;
    const unsigned m  = (unsigned)s | ((unsigned)d << 11) | (fl << 22);
    const int t = pos >> 5, i = pos & 31;                 // thread t, local slot i
    meta[(((i >> 2) * NTE) + t) * 4 + (i & 3)] = m;       // int4-tiled [i/4][t][i%4]
    csr_pos[e] = (unsigned)pos;
}

// ---- GAT: 1 block/graph; LDS-permuted weights + register segmented reduction ----

__global__ __launch_bounds__(1024) void gat_csr(
    const float* __restrict__ x, const float* __restrict__ edge_w,
    const unsigned* __restrict__ csr_pos, const int4* __restrict__ meta4,
    const float* __restrict__ W_node, const float* __restrict__ W_edge,
    const float* __restrict__ attn_l, const float* __restrict__ attn_e,
    const float* __restrict__ attn_r, const float* __restrict__ gat_b,
    float* __restrict__ feats)
{
    __shared__ float wsp[N_EDGES];     // 128 KB: edge weights in CSR order
    __shared__ float xs[N_NODES];      // 8 KB
    __shared__ int   hn[NTE];          // 4 KB: head-partial node id (-1 = empty)
    __shared__ float hp0[NTE], hp1[NTE], hp2[NTE];   // 12 KB: head partials
    __shared__ double wr1[16], wr2[16];

    const int g   = blockIdx.x;
    const int tid = threadIdx.x;

    // rank-1 projections collapse to 3 scalars
    float cl = 0.f, ce = 0.f, cr = 0.f;
#pragma unroll
    for (int k = 0; k < OUTF; ++k) {
        cl += W_node[k] * attn_l[k];
        cr += W_node[k] * attn_r[k];
        ce += W_edge[k] * attn_e[k];
    }

    // stage: coalesced read of edge_w, scatter into CSR order in LDS
    {
        const float4* ew4 = (const float4*)(edge_w + (size_t)g * N_EDGES);
        const int4*   cp4 = (const int4*)csr_pos;
#pragma unroll
        for (int k = 0; k < 8; ++k) {
            const int c = tid + k * 1024;
            if (c < N_EDGES / 4) {
                const float4 wv = ew4[c];
                const int4   pv = cp4[c];
                wsp[pv.x] = wv.x; wsp[pv.y] = wv.y; wsp[pv.z] = wv.z; wsp[pv.w] = wv.w;
            }
        }
        if (tid < N_NODES / 4)
            ((float4*)xs)[tid] = ((const float4*)(x + (size_t)g * N_NODES))[tid];
    }
    __syncthreads();

    double s1 = 0.0, s2 = 0.0;
    float den = 0.f, t1 = 0.f, t2 = 0.f;
    int   cur = -1;
    int   headdone = 0;

    if (tid < NTE) {
        const int p0 = tid * EPT;
        float4 wv; int4 mv;
#pragma unroll
        for (int i = 0; i < EPT; ++i) {
            if ((i & 3) == 0) {
                wv = *(const float4*)&wsp[p0 + i];          // ds_read_b128, contiguous
                mv = meta4[(i >> 2) * NTE + tid];           // coalesced int4 global
            }
            const float w = ((i & 3) == 0) ? wv.x : ((i & 3) == 1) ? wv.y
                          : ((i & 3) == 2) ? wv.z : wv.w;
            const int   m = ((i & 3) == 0) ? mv.x : ((i & 3) == 1) ? mv.y
                          : ((i & 3) == 2) ? mv.z : mv.w;
            const int s = m & 2047;
            const int d = (m >> 11) & 2047;
            if (m & (1 << 22)) {              // segment (dst) starts at this position
                if (headdone) {               // interior segment: finalize in registers
                    s1 += (double)(t1 / den);
                    s2 += (double)(t2 / den);
                } else {                      // first boundary: publish head partial
                    hn[tid] = cur; hp0[tid] = den; hp1[tid] = t1; hp2[tid] = t2;
                    headdone = 1;
                }
                den = 0.f; t1 = 0.f; t2 = 0.f;
                cur = d;
            } else if (i == 0) {
                cur = d;                      // continuation of previous thread's segment
            }
            const float xsv = xs[s];
            const float ev0 = cl * xsv + ce * w + cr * xs[d];
            const float ev  = fmaxf(ev0, 0.2f * ev0);      // leaky_relu
            const float num = __expf(ev);                  // softmax ratio-invariant shift
            den += num; t1 += num * xsv; t2 += num * w;
        }
        if (!headdone) {   // whole range is one continuation: publish as head
            hn[tid] = cur; hp0[tid] = den; hp1[tid] = t1; hp2[tid] = t2;
        }
    }
    __syncthreads();

    // owner of trailing run collects continuations from following threads
    if (tid < NTE && headdone) {
        int tn = tid + 1;
        while (tn < NTE && hn[tn] == cur) {
            den += hp0[tn]; t1 += hp1[tn]; t2 += hp2[tn]; ++tn;
        }
        s1 += (double)(t1 / den);
        s2 += (double)(t2 / den);
    }

    // block reduction (f64)
#pragma unroll
    for (int off = 32; off > 0; off >>= 1) {
        s1 += __shfl_down(s1, off, 64);
        s2 += __shfl_down(s2, off, 64);
    }
    const int wave = tid >> 6, lane = tid & 63;
    if (lane == 0) { wr1[wave] = s1; wr2[wave] = s2; }
    __syncthreads();
    if (tid == 0) {
        double a = 0.0, c = 0.0;
#pragma unroll
        for (int w = 0; w < 16; ++w) { a += wr1[w]; c += wr2[w]; }
#pragma unroll
        for (int k = 0; k < OUTF; ++k)
            feats[g * OUTF + k] = gat_b[k] +
                (float)((a * (double)W_node[k] + c * (double)W_edge[k]) / (double)N_NODES);
    }
}

// ---------------- head: 16 blocks (one per batch): LSTM + precomputed-M projection ----------------

__device__ __forceinline__ float fast_sigmoid(float v) {
    return 1.f / (1.f + __expf(-v));
}
__device__ __forceinline__ float fast_tanh(float v) {
    float t = __expf(2.f * v);
    return (t - 1.f) / (t + 1.f);
}

__global__ __launch_bounds__(128) void lstm_head(
    const float* __restrict__ feats, const float* __restrict__ Mw,
    const float* __restrict__ b2w,
    const float* __restrict__ w_ih, const float* __restrict__ w_hh,
    const float* __restrict__ b_ih, const float* __restrict__ b_hh,
    float* __restrict__ out)
{
    __shared__ float s_M[FCC_OUTD * HID];
    __shared__ float s_b2[FCC_OUTD];
    __shared__ float s_xt[TT * OUTF];
    __shared__ float s_bias[96];
    __shared__ float s_xg[TT * 96];
    __shared__ float s_g[96];
    __shared__ float s_h[HID], s_c[HID];
    __shared__ float s_hs[TT * HID];

    const int b   = blockIdx.x;
    const int tid = threadIdx.x;

    for (int i = tid; i < FCC_OUTD * HID; i += 128) s_M[i] = Mw[i];
    if (tid < FCC_OUTD) s_b2[tid] = b2w[tid];
    for (int i = tid; i < TT * OUTF; i += 128) s_xt[i] = feats[b * TT * OUTF + i];
    if (tid < 96) s_bias[tid] = b_ih[tid] + b_hh[tid];
    if (tid < HID) { s_h[tid] = 0.f; s_c[tid] = 0.f; }

    float rw_hh[HID];
    if (tid < 96) {
#pragma unroll
        for (int k = 0; k < HID; ++k) rw_hh[k] = w_hh[tid * HID + k];
    }
    __syncthreads();

    for (int u = tid; u < TT * 96; u += 128) {
        const int t = u / 96, j = u % 96;
        float acc = s_bias[j];
        const float* xt = &s_xt[t * OUTF];
#pragma unroll
        for (int k = 0; k < OUTF; ++k) acc += xt[k] * w_ih[j * OUTF + k];
        s_xg[u] = acc;
    }
    __syncthreads();

    for (int t = 0; t < TT; ++t) {
        if (tid < 96) {
            float acc = s_xg[t * 96 + tid];
#pragma unroll
            for (int k = 0; k < HID; ++k) acc += s_h[k] * rw_hh[k];
            s_g[tid] = acc;
        }
        __syncthreads();
        if (tid < HID) {
            const float i_ = fast_sigmoid(s_g[tid]);
            const float f_ = fast_sigmoid(s_g[24 + tid]);
            const float g_ = fast_tanh(s_g[48 + tid]);
            const float o_ = fast_sigmoid(s_g[72 + tid]);
            const float c = f_ * s_c[tid] + i_ * g_;
            s_c[tid] = c;
            const float h = o_ * fast_tanh(c);
            s_h[tid] = h;
            s_hs[t * HID + tid] = h;
        }
        __syncthreads();
    }

    for (int u = tid; u < TT * FCC_OUTD; u += 128) {
        const int t = u / FCC_OUTD, j = u % FCC_OUTD;
        float acc = s_b2[j];
        const float* hr = &s_hs[t * HID];
#pragma unroll
        for (int h = 0; h < HID; ++h) acc += hr[h] * s_M[j * HID + h];
        out[(b * TT + t) * FCC_OUTD + j] = acc;
    }
}

extern "C" void kernel_launch(void* const* d_in, const int* in_sizes, int n_in,
                              void* d_out, int out_size, void* d_ws, size_t ws_size,
                              hipStream_t stream) {
    const float* x      = (const float*)d_in[0];
    const float* edge_w = (const float*)d_in[1];
    const int*   src    = (const int*)d_in[2];
    const int*   dst    = (const int*)d_in[3];
    const float* W_node = (const float*)d_in[4];
    const float* W_edge = (const float*)d_in[5];
    const float* attn_l = (const float*)d_in[6];
    const float* attn_e = (const float*)d_in[7];
    const float* attn_r = (const float*)d_in[8];
    const float* gat_b  = (const float*)d_in[9];
    const float* w_ih   = (const float*)d_in[10];
    const float* w_hh   = (const float*)d_in[11];
    const float* b_ih   = (const float*)d_in[12];
    const float* b_hh   = (const float*)d_in[13];
    const float* fc_w   = (const float*)d_in[14];
    const float* fc_b   = (const float*)d_in[15];
    const float* fcc_w  = (const float*)d_in[16];
    const float* fcc_b  = (const float*)d_in[17];

    char* ws = (char*)d_ws;
    unsigned* csr_pos = (unsigned*)(ws + WS_CSRPOS);
    unsigned* meta    = (unsigned*)(ws + WS_META);
    int*      row_ptr = (int*)(ws + WS_ROWPTR);
    int*      cursor  = (int*)(ws + WS_CURSOR);
    float*    feats   = (float*)(ws + WS_FEATS);
    float*    Mw      = (float*)(ws + WS_M);
    float*    b2w     = (float*)(ws + WS_B2);
    float*    out     = (float*)d_out;

    build_hist_scan<<<1, 1024, 0, stream>>>(dst, row_ptr, cursor);
    build_scatter<<<33, 1024, 0, stream>>>(src, dst, row_ptr, cursor, meta, csr_pos,
                                           fc_w, fc_b, fcc_w, fcc_b, Mw, b2w);
    gat_csr<<<NG, 1024, 0, stream>>>(x, edge_w, csr_pos, (const int4*)meta,
                                     W_node, W_edge, attn_l, attn_e, attn_r, gat_b, feats);
    lstm_head<<<BB, 128, 0, stream>>>(feats, Mw, b2w, w_ih, w_hh, b_ih, b_hh, out);
}